// Round 11
// baseline (299.290 us; speedup 1.0000x reference)
//
#include <hip/hip_runtime.h>

typedef int v4i __attribute__((ext_vector_type(4)));
typedef unsigned int u32;
typedef __attribute__((address_space(1))) const u32 gas_u32;
typedef __attribute__((address_space(3))) u32 las_u32;

#define THREADS 512
#define NWAVES 8
#define EPT 32                           // edges per thread per chunk
#define CHUNK (THREADS * EPT)            // 16384
#define NBLK 256                         // persistent: 1 block per CU
#define PART_BITS 19
#define PART_NODES (1 << PART_BITS)      // 524288 nodes per partition
#define PART_WORDS (PART_NODES / 16)     // 32768 words = 128 KB
#define NPART 2
#define TBL 450                          // NUM_RELS * 9
#define FILL_WAVE_WORDS (PART_WORDS / NWAVES)  // 4096 words per wave
#define FILL_PER_WAVE (FILL_WAVE_WORDS / 256)  // 16 DMA instrs per wave
#define PAD_WIDX ((u32)PART_WORDS)             // zeroed pad word index

// Barrier WITHOUT vmcnt drain (DMA/stream loads stay in flight); rule-18 fence.
#define BAR() do {                                            \
    asm volatile("s_waitcnt lgkmcnt(0)" ::: "memory");        \
    __builtin_amdgcn_s_barrier();                             \
    __builtin_amdgcn_sched_barrier(0);                        \
} while (0)

// Counted vmcnt wait (T4): keep the N newest loads in flight.
#define WAITVM(n) do {                                        \
    asm volatile("s_waitcnt vmcnt(" #n ")" ::: "memory");     \
    __builtin_amdgcn_sched_barrier(0);                        \
} while (0)

__global__ void zero_kernel(float* __restrict__ out, int n) {
    int i = blockIdx.x * blockDim.x + threadIdx.x;
    if (i < n) out[i] = 0.0f;
}

// Pack node_type (0..2) into 2 bits/node: 16 nodes per uint32 (256 KB total).
__global__ void pack_nt_kernel(const int* __restrict__ nt,
                               unsigned int* __restrict__ packed,
                               int nwords, int N) {
    int i = blockIdx.x * blockDim.x + threadIdx.x;
    if (i >= nwords) return;
    unsigned int word = 0;
    int base = i * 16;
    if (base + 16 <= N) {
        #pragma unroll
        for (int j = 0; j < 4; ++j) {
            int4 v = *reinterpret_cast<const int4*>(nt + base + j * 4);
            word |= (unsigned)(v.x & 3) << (2 * (j * 4 + 0));
            word |= (unsigned)(v.y & 3) << (2 * (j * 4 + 1));
            word |= (unsigned)(v.z & 3) << (2 * (j * 4 + 2));
            word |= (unsigned)(v.w & 3) << (2 * (j * 4 + 3));
        }
    } else {
        for (int j = 0; base + j < N; ++j)
            word |= (unsigned)(nt[base + j] & 3) << (2 * j);
    }
    packed[i] = word;
}

// DMA one 128 KB partition p into the single LDS buffer. Wave-uniform LDS
// base + lane x 16B (m104 pattern); per-lane global source. Zero VGPR cost.
__device__ __forceinline__ void dma_fill(const u32* __restrict__ pnt,
                                         u32* lds0, int p, int wv, int lane) {
    const u32* g = pnt + (size_t)p * PART_WORDS + wv * FILL_WAVE_WORDS + lane * 4;
    u32* l = lds0 + wv * FILL_WAVE_WORDS;
    #pragma unroll
    for (int i = 0; i < FILL_PER_WAVE; ++i)
        __builtin_amdgcn_global_load_lds((gas_u32*)(g + i * 256),
                                         (las_u32*)(l + i * 256), 16, 0, 0);
}

// Gather pass for compile-time partition P; addresses computed inline.
// Out-of-partition lanes read the zeroed pad word (uniform addr = broadcast);
// bfe of 0 contributes 0, so the accumulate is unconditional.
template <int P>
__device__ __forceinline__ void gather_phase(const u32* lds_all,
                                             const int (&sv)[EPT], const int (&dv)[EPT],
                                             int (&enc)[EPT]) {
    #pragma unroll
    for (int k = 0; k < EPT; ++k) {
        u32 s = (u32)sv[k];
        u32 idx_s = ((s >> PART_BITS) == (u32)P)
                        ? ((s & (u32)(PART_NODES - 1)) >> 4) : PAD_WIDX;
        u32 word_s = lds_all[idx_s];
        u32 d = (u32)dv[k];
        u32 idx_d = ((d >> PART_BITS) == (u32)P)
                        ? ((d & (u32)(PART_NODES - 1)) >> 4) : PAD_WIDX;
        u32 word_d = lds_all[idx_d];
        enc[k] += (int)((word_s >> ((s & 15u) << 1)) & 3u) * 3;
        enc[k] += (int)((word_d >> ((d & 15u) << 1)) & 3u);
    }
}

// 512 threads / __launch_bounds__(512,2): 2 waves/EU floor -> 256-VGPR budget.
// LDS (130 KB) caps at 1 block/CU anyway, so the fat register file is free.
__launch_bounds__(THREADS, 2)
__global__ void edge_score_k(const u32* __restrict__ pnt,
                             const int* __restrict__ et_g,
                             const int* __restrict__ es_g,
                             const int* __restrict__ ed_g,
                             const int* __restrict__ eb_g,
                             const float* __restrict__ wt,
                             float* __restrict__ out,
                             int nchunk) {
    // [0, 32768): 128 KB partition buffer | [32768, 32784): zero pad |
    // then the 450-entry weight table.
    __shared__ __align__(16) u32 lds_all[PART_WORDS + 16 + TBL];
    float* lw = reinterpret_cast<float*>(lds_all + PART_WORDS + 16);

    const int tid  = threadIdx.x;
    const int lane = tid & 63;
    const int wv   = tid >> 6;

    if (tid < 16) lds_all[PART_WORDS + tid] = 0u;   // zero pad words
    for (int i = tid; i < TBL; i += THREADS) lw[i] = wt[i];

    const long blk0 = (long)blockIdx.x * ((long)nchunk * CHUNK);
    const long lb   = (long)wv * (64 * EPT) + (long)lane * 4;   // wave window 2048

    // prologue: streams for chunk 0 (24 nontemporal dwordx4 loads)
    v4i etv[8], svv[8], dvv[8];
    #pragma unroll
    for (int j = 0; j < 8; ++j) {
        etv[j] = __builtin_nontemporal_load((const v4i*)(et_g + blk0 + lb + j * 256));
        svv[j] = __builtin_nontemporal_load((const v4i*)(es_g + blk0 + lb + j * 256));
        dvv[j] = __builtin_nontemporal_load((const v4i*)(ed_g + blk0 + lb + j * 256));
    }

    for (int c = 0; c < nchunk; ++c) {
        const long cb = blk0 + (long)c * CHUNK + lb;

        // ---------------- phase A: fill p0 + unpack + gather<0> ----------------
        BAR();                               // prev gather<1>+epilogue done: buf free
        dma_fill(pnt, lds_all, 0, wv, lane); // 16 DMA -> buf
        __builtin_amdgcn_sched_barrier(0);   // pin DMA issue before unpack

        int enc[EPT], sv[EPT], dv[EPT];
        #pragma unroll
        for (int j = 0; j < 8; ++j) {
            // auto-wait here is vmcnt(16): streams retired, p0 fill in flight
            #pragma unroll
            for (int q = 0; q < 4; ++q) {
                enc[j * 4 + q] = etv[j][q] * 9;
                sv[j * 4 + q]  = svv[j][q];
                dv[j * 4 + q]  = dvv[j][q];
            }
        }
        WAITVM(0);                           // own p0 fill landed
        BAR();                               // p0 resident blockwide
        gather_phase<0>(lds_all, sv, dv, enc);

        // ---------------- phase B: fill p1 + eb + next streams + gather<1> -----
        BAR();                               // gather<0> done: buf free
        dma_fill(pnt, lds_all, 1, wv, lane); // 16 DMA -> buf
        __builtin_amdgcn_sched_barrier(0);
        v4i ebv[8];
        #pragma unroll
        for (int j = 0; j < 8; ++j)
            ebv[j] = __builtin_nontemporal_load((const v4i*)(eb_g + cb + j * 256));
        {   // next-chunk streams (clamped on last chunk: keeps vmcnt uniform)
            long nb = (c + 1 < nchunk) ? (cb + CHUNK) : cb;
            #pragma unroll
            for (int j = 0; j < 8; ++j) {
                etv[j] = __builtin_nontemporal_load((const v4i*)(et_g + nb + j * 256));
                svv[j] = __builtin_nontemporal_load((const v4i*)(es_g + nb + j * 256));
                dvv[j] = __builtin_nontemporal_load((const v4i*)(ed_g + nb + j * 256));
            }
        }
        WAITVM(32);                          // p1 fill landed; eb(8)+streams(24) in flight
        BAR();                               // p1 resident blockwide
        gather_phase<1>(lds_all, sv, dv, enc);

        // ---------------- epilogue ----------------
        float val[EPT];
        #pragma unroll
        for (int k = 0; k < EPT; ++k) val[k] = lw[enc[k]];

        WAITVM(24);                          // eb landed; next streams stay in flight
        int wb0 = __shfl(ebv[0][0], 0);      // first edge of wave window
        int wbL = __shfl(ebv[7][3], 63);     // last edge of wave window
        if (wb0 == wbL) {                    // sorted => whole window one graph
            float ssum = 0.0f;
            #pragma unroll
            for (int k = 0; k < EPT; ++k) ssum += val[k];
            #pragma unroll
            for (int off = 32; off >= 1; off >>= 1)
                ssum += __shfl_down(ssum, off);
            if (lane == 0) atomicAdd(&out[wb0], ssum);
        } else {
            float acc = 0.0f; int cur = -1;
            #pragma unroll
            for (int k = 0; k < EPT; ++k) {
                int bb = ebv[k / 4][k % 4];  // static index
                if (bb != cur) {
                    if (cur >= 0) atomicAdd(&out[cur], acc);
                    cur = bb; acc = 0.0f;
                }
                acc += val[k];
            }
            if (cur >= 0) atomicAdd(&out[cur], acc);
        }
    }
}

// Per-edge fallback / tail kernel (direct gathers; correctness path).
__global__ void edge_score_simple(const int* __restrict__ nt,
                                  const int* __restrict__ et,
                                  const int* __restrict__ es,
                                  const int* __restrict__ ed,
                                  const int* __restrict__ eb,
                                  const float* __restrict__ w,
                                  float* __restrict__ out,
                                  long e0, long E) {
    long e = e0 + (long)blockIdx.x * blockDim.x + threadIdx.x;
    if (e >= E) return;
    int enc = et[e] * 9 + nt[es[e]] * 3 + nt[ed[e]];
    atomicAdd(&out[eb[e]], w[enc]);
}

extern "C" void kernel_launch(void* const* d_in, const int* in_sizes, int n_in,
                              void* d_out, int out_size, void* d_ws, size_t ws_size,
                              hipStream_t stream) {
    const int*   node_type  = (const int*)d_in[0];
    const int*   edge_type  = (const int*)d_in[1];
    const int*   edge_index = (const int*)d_in[2];   // [2, E]: src then dst
    const int*   edge_batch = (const int*)d_in[3];
    const float* w          = (const float*)d_in[4];
    float* out = (float*)d_out;

    long N = in_sizes[0];
    long E = in_sizes[1];
    const int* esrc = edge_index;
    const int* edst = edge_index + E;

    // d_out is poisoned once and never re-poisoned between replays; we
    // accumulate with atomics, so zero it at the start of every launch.
    zero_kernel<<<(out_size + 255) / 256, 256, 0, stream>>>(out, out_size);

    int  nwords = (int)((N + 15) / 16);
    long nchunk = E / ((long)NBLK * CHUNK);            // 4 for E = 2^24
    bool fast_ok = (ws_size >= (size_t)nwords * 4) &&
                   (N <= (long)NPART * PART_NODES) && (nchunk > 0);

    if (fast_ok) {
        unsigned int* pnt = (unsigned int*)d_ws;
        pack_nt_kernel<<<(nwords + 255) / 256, 256, 0, stream>>>(node_type, pnt, nwords, (int)N);

        edge_score_k<<<NBLK, THREADS, 0, stream>>>(
            pnt, edge_type, esrc, edst, edge_batch, w, out, (int)nchunk);

        long covered = (long)NBLK * nchunk * CHUNK;
        long rem     = E - covered;                    // 0 for this dataset
        if (rem > 0) {
            int tb = (int)((rem + 255) / 256);
            edge_score_simple<<<tb, 256, 0, stream>>>(
                node_type, edge_type, esrc, edst, edge_batch, w, out, covered, E);
        }
    } else {
        int tb = (int)((E + 255) / 256);
        edge_score_simple<<<tb, 256, 0, stream>>>(
            node_type, edge_type, esrc, edst, edge_batch, w, out, 0, E);
    }
}

// Round 12
// 256.125 us; speedup vs baseline: 1.1685x; 1.1685x over previous
//
#include <hip/hip_runtime.h>

typedef int v4i __attribute__((ext_vector_type(4)));
typedef unsigned int u32;
typedef __attribute__((address_space(1))) const u32 gas_u32;
typedef __attribute__((address_space(3))) u32 las_u32;

#define THREADS 1024
#define NWAVES 16
#define EPT 16                           // edges per thread per chunk
#define CHUNK (THREADS * EPT)            // 16384
#define NBLK 256                         // persistent: 1 block per CU
#define PART_BITS 19
#define PART_NODES (1 << PART_BITS)      // 524288 nodes per partition
#define PART_WORDS (PART_NODES / 16)     // 32768 words = 128 KB
#define NPART 2
#define TBL 450                          // NUM_RELS * 9
#define FILL_WAVE_WORDS (PART_WORDS / NWAVES)  // 2048 words per wave
#define FILL_PER_WAVE (FILL_WAVE_WORDS / 256)  // 8 DMA instrs per wave
#define PAD_WIDX ((u32)PART_WORDS)             // zeroed pad word index

// Barrier WITHOUT vmcnt drain (DMA/stream loads stay in flight); rule-18 fence.
#define BAR() do {                                            \
    asm volatile("s_waitcnt lgkmcnt(0)" ::: "memory");        \
    __builtin_amdgcn_s_barrier();                             \
    __builtin_amdgcn_sched_barrier(0);                        \
} while (0)

// Counted vmcnt wait (T4): keep the N newest loads in flight.
#define WAITVM(n) do {                                        \
    asm volatile("s_waitcnt vmcnt(" #n ")" ::: "memory");     \
    __builtin_amdgcn_sched_barrier(0);                        \
} while (0)

__global__ void zero_kernel(float* __restrict__ out, int n) {
    int i = blockIdx.x * blockDim.x + threadIdx.x;
    if (i < n) out[i] = 0.0f;
}

// Pack node_type (0..2) into 2 bits/node: 16 nodes per uint32 (256 KB total).
__global__ void pack_nt_kernel(const int* __restrict__ nt,
                               unsigned int* __restrict__ packed,
                               int nwords, int N) {
    int i = blockIdx.x * blockDim.x + threadIdx.x;
    if (i >= nwords) return;
    unsigned int word = 0;
    int base = i * 16;
    if (base + 16 <= N) {
        #pragma unroll
        for (int j = 0; j < 4; ++j) {
            int4 v = *reinterpret_cast<const int4*>(nt + base + j * 4);
            word |= (unsigned)(v.x & 3) << (2 * (j * 4 + 0));
            word |= (unsigned)(v.y & 3) << (2 * (j * 4 + 1));
            word |= (unsigned)(v.z & 3) << (2 * (j * 4 + 2));
            word |= (unsigned)(v.w & 3) << (2 * (j * 4 + 3));
        }
    } else {
        for (int j = 0; base + j < N; ++j)
            word |= (unsigned)(nt[base + j] & 3) << (2 * j);
    }
    packed[i] = word;
}

// DMA one 128 KB partition into the single LDS buffer. Wave-uniform LDS base
// + lane x 16B (m104 pattern); per-lane global source. Zero VGPR cost.
__device__ __forceinline__ void dma_fill(const u32* __restrict__ pnt,
                                         u32* lds0, int p, int wv, int lane) {
    const u32* g = pnt + (size_t)p * PART_WORDS + wv * FILL_WAVE_WORDS + lane * 4;
    u32* l = lds0 + wv * FILL_WAVE_WORDS;
    #pragma unroll
    for (int i = 0; i < FILL_PER_WAVE; ++i)
        __builtin_amdgcn_global_load_lds((gas_u32*)(g + i * 256),
                                         (las_u32*)(l + i * 256), 16, 0, 0);
}

// Gather pass for compile-time partition P. ax = part(1b)<<20 | widx(15b)<<5
// | shift(5b) -- one packed reg per endpoint, nothing left for CSE to hoist.
// Out-of-partition lanes read the zeroed pad word (broadcast); contribution
// auto-vanishes, so the accumulate is unconditional.
template <int P>
__device__ __forceinline__ void gather_phase(const u32* lds_all,
                                             const u32 (&axs)[EPT], const u32 (&axd)[EPT],
                                             int (&enc)[EPT]) {
    #pragma unroll
    for (int k = 0; k < EPT; ++k) {
        u32 as = axs[k];
        u32 idx_s = ((as >> 20) == (u32)P) ? ((as >> 5) & 0x7FFFu) : PAD_WIDX;
        u32 ws = lds_all[idx_s];
        u32 ad = axd[k];
        u32 idx_d = ((ad >> 20) == (u32)P) ? ((ad >> 5) & 0x7FFFu) : PAD_WIDX;
        u32 wd = lds_all[idx_d];
        int ts = (int)((ws >> (as & 31u)) & 3u);
        int td = (int)((wd >> (ad & 31u)) & 3u);
        enc[k] += ts * 3 + td;
    }
}

// waves_per_eu(4,4) pins exactly 16 waves/CU (the 133 KB LDS forces 1 block
// anyway) -> 128-VGPR budget instead of the 64-reg jail of rounds 7-10.
__global__ __launch_bounds__(THREADS)
__attribute__((amdgpu_waves_per_eu(4, 4)))
void edge_score_k(const u32* __restrict__ pnt,
                  const int* __restrict__ et_g,
                  const int* __restrict__ es_g,
                  const int* __restrict__ ed_g,
                  const int* __restrict__ eb_g,
                  const float* __restrict__ wt,
                  float* __restrict__ out,
                  int nchunk) {
    // [0, 32768): 128 KB partition buffer | [32768, 32784): zero pad |
    // then the 450-entry weight table.
    __shared__ __align__(16) u32 lds_all[PART_WORDS + 16 + TBL];
    float* lw = reinterpret_cast<float*>(lds_all + PART_WORDS + 16);

    const int tid  = threadIdx.x;
    const int lane = tid & 63;
    const int wv   = tid >> 6;

    if (tid < 16) lds_all[PART_WORDS + tid] = 0u;   // zero pad words
    // lw fill FIRST (its global load sits oldest in the vmcnt ledger).
    for (int i = tid; i < TBL; i += THREADS) lw[i] = wt[i];

    const long blk0 = (long)blockIdx.x * ((long)nchunk * CHUNK);
    const long lb   = (long)wv * (64 * EPT) + (long)lane * 4;   // wave window 1024

    // prologue: streams for chunk 0 (12 nontemporal dwordx4 loads)
    v4i etv[4], svv[4], dvv[4];
    #pragma unroll
    for (int j = 0; j < 4; ++j) {
        etv[j] = __builtin_nontemporal_load((const v4i*)(et_g + blk0 + lb + j * 256));
        svv[j] = __builtin_nontemporal_load((const v4i*)(es_g + blk0 + lb + j * 256));
        dvv[j] = __builtin_nontemporal_load((const v4i*)(ed_g + blk0 + lb + j * 256));
    }

    for (int c = 0; c < nchunk; ++c) {
        const long cb = blk0 + (long)c * CHUNK + lb;

        // ---------------- phase A: fill p0 + unpack + gather<0> ----------------
        BAR();                               // prev gather<1>+epilogue done: buf free
        dma_fill(pnt, lds_all, 0, wv, lane); // 8 DMA -> buf
        __builtin_amdgcn_sched_barrier(0);
        WAITVM(8);                           // streams landed; p0 fill in flight

        int enc[EPT]; u32 axs[EPT], axd[EPT];
        #pragma unroll
        for (int j = 0; j < 4; ++j) {
            #pragma unroll
            for (int q = 0; q < 4; ++q) {
                int k = j * 4 + q;
                enc[k] = etv[j][q] * 9;
                u32 s = (u32)svv[j][q];
                u32 d = (u32)dvv[j][q];
                axs[k] = ((s >> PART_BITS) << 20) | (((s >> 4) & 0x7FFFu) << 5) | ((s & 15u) << 1);
                axd[k] = ((d >> PART_BITS) << 20) | (((d >> 4) & 0x7FFFu) << 5) | ((d & 15u) << 1);
            }
        }
        WAITVM(0);                           // own p0 fill landed (issued 1 phase early)
        BAR();                               // p0 resident blockwide
        gather_phase<0>(lds_all, axs, axd, enc);

        // ---------------- phase B: fill p1 + eb + next streams + gather<1> -----
        BAR();                               // gather<0> done: buf free
        dma_fill(pnt, lds_all, 1, wv, lane); // 8 DMA -> buf
        __builtin_amdgcn_sched_barrier(0);
        v4i ebv[4];
        #pragma unroll
        for (int j = 0; j < 4; ++j)
            ebv[j] = __builtin_nontemporal_load((const v4i*)(eb_g + cb + j * 256));
        {   // next-chunk streams (clamped on last chunk: keeps vmcnt uniform)
            long nb = (c + 1 < nchunk) ? (cb + CHUNK) : cb;
            #pragma unroll
            for (int j = 0; j < 4; ++j) {
                etv[j] = __builtin_nontemporal_load((const v4i*)(et_g + nb + j * 256));
                svv[j] = __builtin_nontemporal_load((const v4i*)(es_g + nb + j * 256));
                dvv[j] = __builtin_nontemporal_load((const v4i*)(ed_g + nb + j * 256));
            }
        }
        WAITVM(16);                          // p1 fill landed; eb(4)+streams(12) in flight
        BAR();                               // p1 resident blockwide
        gather_phase<1>(lds_all, axs, axd, enc);

        // ---------------- epilogue ----------------
        WAITVM(12);                          // eb landed; next streams stay in flight
        int wb0 = __shfl(ebv[0][0], 0);      // first edge of wave window
        int wbL = __shfl(ebv[3][3], 63);     // last edge of wave window
        if (wb0 == wbL) {                    // sorted => whole window one graph
            float ssum = 0.0f;
            #pragma unroll
            for (int k = 0; k < EPT; ++k) ssum += lw[enc[k]];
            #pragma unroll
            for (int off = 32; off >= 1; off >>= 1)
                ssum += __shfl_down(ssum, off);
            if (lane == 0) atomicAdd(&out[wb0], ssum);
        } else {
            float acc = 0.0f; int cur = -1;
            #pragma unroll
            for (int k = 0; k < EPT; ++k) {
                int bb = ebv[k / 4][k % 4];  // static index
                if (bb != cur) {
                    if (cur >= 0) atomicAdd(&out[cur], acc);
                    cur = bb; acc = 0.0f;
                }
                acc += lw[enc[k]];
            }
            if (cur >= 0) atomicAdd(&out[cur], acc);
        }
    }
}

// Per-edge fallback / tail kernel (direct gathers; correctness path).
__global__ void edge_score_simple(const int* __restrict__ nt,
                                  const int* __restrict__ et,
                                  const int* __restrict__ es,
                                  const int* __restrict__ ed,
                                  const int* __restrict__ eb,
                                  const float* __restrict__ w,
                                  float* __restrict__ out,
                                  long e0, long E) {
    long e = e0 + (long)blockIdx.x * blockDim.x + threadIdx.x;
    if (e >= E) return;
    int enc = et[e] * 9 + nt[es[e]] * 3 + nt[ed[e]];
    atomicAdd(&out[eb[e]], w[enc]);
}

extern "C" void kernel_launch(void* const* d_in, const int* in_sizes, int n_in,
                              void* d_out, int out_size, void* d_ws, size_t ws_size,
                              hipStream_t stream) {
    const int*   node_type  = (const int*)d_in[0];
    const int*   edge_type  = (const int*)d_in[1];
    const int*   edge_index = (const int*)d_in[2];   // [2, E]: src then dst
    const int*   edge_batch = (const int*)d_in[3];
    const float* w          = (const float*)d_in[4];
    float* out = (float*)d_out;

    long N = in_sizes[0];
    long E = in_sizes[1];
    const int* esrc = edge_index;
    const int* edst = edge_index + E;

    // d_out is poisoned once and never re-poisoned between replays; we
    // accumulate with atomics, so zero it at the start of every launch.
    zero_kernel<<<(out_size + 255) / 256, 256, 0, stream>>>(out, out_size);

    int  nwords = (int)((N + 15) / 16);
    long nchunk = E / ((long)NBLK * CHUNK);            // 4 for E = 2^24
    bool fast_ok = (ws_size >= (size_t)nwords * 4) &&
                   (N <= (long)NPART * PART_NODES) && (nchunk > 0);

    if (fast_ok) {
        unsigned int* pnt = (unsigned int*)d_ws;
        pack_nt_kernel<<<(nwords + 255) / 256, 256, 0, stream>>>(node_type, pnt, nwords, (int)N);

        edge_score_k<<<NBLK, THREADS, 0, stream>>>(
            pnt, edge_type, esrc, edst, edge_batch, w, out, (int)nchunk);

        long covered = (long)NBLK * nchunk * CHUNK;
        long rem     = E - covered;                    // 0 for this dataset
        if (rem > 0) {
            int tb = (int)((rem + 255) / 256);
            edge_score_simple<<<tb, 256, 0, stream>>>(
                node_type, edge_type, esrc, edst, edge_batch, w, out, covered, E);
        }
    } else {
        int tb = (int)((E + 255) / 256);
        edge_score_simple<<<tb, 256, 0, stream>>>(
            node_type, edge_type, esrc, edst, edge_batch, w, out, 0, E);
    }
}

// Round 13
// 154.789 us; speedup vs baseline: 1.9335x; 1.6547x over previous
//
#include <hip/hip_runtime.h>

typedef int v4i __attribute__((ext_vector_type(4)));
typedef unsigned int u32;
typedef __attribute__((address_space(1))) const u32 gas_u32;
typedef __attribute__((address_space(3))) u32 las_u32;

#define THREADS 512
#define NWAVES 8
#define EPT 8                            // edges per thread per chunk
#define CHUNK (THREADS * EPT)            // 4096
#define NBLK2 512                        // 2 blocks per CU (TLP fill-cover)
#define PART_BITS 18
#define PART_NODES (1 << PART_BITS)      // 262144 nodes per partition
#define PART_WORDS (PART_NODES / 16)     // 16384 words = 64 KB
#define NPART 4
#define TBL 450                          // NUM_RELS * 9
#define FILL_WAVE_WORDS (PART_WORDS / NWAVES)  // 2048 words per wave
#define FILL_PER_WAVE (FILL_WAVE_WORDS / 256)  // 8 DMA instrs per wave
#define PAD_WIDX ((u32)PART_WORDS)             // zeroed pad word index

// Barrier WITHOUT vmcnt drain; rule-18 fence.
#define BAR() do {                                            \
    asm volatile("s_waitcnt lgkmcnt(0)" ::: "memory");        \
    __builtin_amdgcn_s_barrier();                             \
    __builtin_amdgcn_sched_barrier(0);                        \
} while (0)

// Drain vmcnt (fills must be resident before the visibility barrier).
#define WAITVM0() do {                                        \
    asm volatile("s_waitcnt vmcnt(0)" ::: "memory");          \
    __builtin_amdgcn_sched_barrier(0);                        \
} while (0)

__global__ void zero_kernel(float* __restrict__ out, int n) {
    int i = blockIdx.x * blockDim.x + threadIdx.x;
    if (i < n) out[i] = 0.0f;
}

// Pack node_type (0..2) into 2 bits/node: 16 nodes per uint32 (256 KB total).
__global__ void pack_nt_kernel(const int* __restrict__ nt,
                               unsigned int* __restrict__ packed,
                               int nwords, int N) {
    int i = blockIdx.x * blockDim.x + threadIdx.x;
    if (i >= nwords) return;
    unsigned int word = 0;
    int base = i * 16;
    if (base + 16 <= N) {
        #pragma unroll
        for (int j = 0; j < 4; ++j) {
            int4 v = *reinterpret_cast<const int4*>(nt + base + j * 4);
            word |= (unsigned)(v.x & 3) << (2 * (j * 4 + 0));
            word |= (unsigned)(v.y & 3) << (2 * (j * 4 + 1));
            word |= (unsigned)(v.z & 3) << (2 * (j * 4 + 2));
            word |= (unsigned)(v.w & 3) << (2 * (j * 4 + 3));
        }
    } else {
        for (int j = 0; base + j < N; ++j)
            word |= (unsigned)(nt[base + j] & 3) << (2 * j);
    }
    packed[i] = word;
}

// DMA one 64 KB partition into the block's LDS buffer. Wave-uniform LDS base
// + lane x 16B (m104 pattern); per-lane global source. Zero VGPR cost.
__device__ __forceinline__ void dma_fill(const u32* __restrict__ pnt,
                                         u32* lds0, int p, int wv, int lane) {
    const u32* g = pnt + (size_t)p * PART_WORDS + wv * FILL_WAVE_WORDS + lane * 4;
    u32* l = lds0 + wv * FILL_WAVE_WORDS;
    #pragma unroll
    for (int i = 0; i < FILL_PER_WAVE; ++i)
        __builtin_amdgcn_global_load_lds((gas_u32*)(g + i * 256),
                                         (las_u32*)(l + i * 256), 16, 0, 0);
}

// Gather pass for compile-time partition P. ax = part(2b)<<19 | widx(14b)<<5
// | shift(5b). Out-of-partition lanes read the zeroed pad word (uniform addr
// = broadcast); their contribution auto-vanishes -> unconditional accumulate.
template <int P>
__device__ __forceinline__ void gather_phase(const u32* lds_all,
                                             const u32 (&axs)[EPT], const u32 (&axd)[EPT],
                                             int (&enc)[EPT]) {
    #pragma unroll
    for (int k = 0; k < EPT; ++k) {
        u32 as = axs[k];
        u32 idx_s = ((as >> 19) == (u32)P) ? ((as >> 5) & 0x3FFFu) : PAD_WIDX;
        u32 ws = lds_all[idx_s];
        u32 ad = axd[k];
        u32 idx_d = ((ad >> 19) == (u32)P) ? ((ad >> 5) & 0x3FFFu) : PAD_WIDX;
        u32 wd = lds_all[idx_d];
        int ts = (int)((ws >> (as & 31u)) & 3u);
        int td = (int)((wd >> (ad & 31u)) & 3u);
        enc[k] += ts * 3 + td;
    }
}

// 512 threads -> 128-VGPR budget (R11-measured). 2 blocks/CU: one block's
// exposed fill-waits are covered by the other block's gather compute (TLP,
// m114 mechanism). Simple serial schedule inside each block.
__launch_bounds__(THREADS, 2)
__global__ void edge_score_k(const u32* __restrict__ pnt,
                             const int* __restrict__ et_g,
                             const int* __restrict__ es_g,
                             const int* __restrict__ ed_g,
                             const int* __restrict__ eb_g,
                             const float* __restrict__ wt,
                             float* __restrict__ out,
                             int nchunk) {
    // [0, 16384): 64 KB partition buffer | [16384, 16400): zero pad |
    // then the 450-entry weight table.
    __shared__ __align__(16) u32 lds_all[PART_WORDS + 16 + TBL];
    float* lw = reinterpret_cast<float*>(lds_all + PART_WORDS + 16);

    const int tid  = threadIdx.x;
    const int lane = tid & 63;
    const int wv   = tid >> 6;

    if (tid < 16) lds_all[PART_WORDS + tid] = 0u;   // zero pad words
    for (int i = tid; i < TBL; i += THREADS) lw[i] = wt[i];

    const long blk0 = (long)blockIdx.x * ((long)nchunk * CHUNK);
    const long lb   = (long)wv * (64 * EPT) + (long)lane * 4;   // wave window 512

    for (int c = 0; c < nchunk; ++c) {
        const long cb = blk0 + (long)c * CHUNK + lb;

        // ---- streams for this chunk (8 nontemporal dwordx4 loads) ----
        v4i etv[2], svv[2], dvv[2], ebv[2];
        #pragma unroll
        for (int j = 0; j < 2; ++j) {
            etv[j] = __builtin_nontemporal_load((const v4i*)(et_g + cb + j * 256));
            svv[j] = __builtin_nontemporal_load((const v4i*)(es_g + cb + j * 256));
            dvv[j] = __builtin_nontemporal_load((const v4i*)(ed_g + cb + j * 256));
            ebv[j] = __builtin_nontemporal_load((const v4i*)(eb_g + cb + j * 256));
        }

        // ---- pack per-endpoint descriptors (reused across 4 phases) ----
        int enc[EPT]; u32 axs[EPT], axd[EPT];
        #pragma unroll
        for (int j = 0; j < 2; ++j) {
            #pragma unroll
            for (int q = 0; q < 4; ++q) {
                int k = j * 4 + q;
                enc[k] = etv[j][q] * 9;    // compiler auto-waits streams here
                u32 s = (u32)svv[j][q];
                u32 d = (u32)dvv[j][q];
                axs[k] = ((s >> PART_BITS) << 19) | (((s >> 4) & 0x3FFFu) << 5) | ((s & 15u) << 1);
                axd[k] = ((d >> PART_BITS) << 19) | (((d >> 4) & 0x3FFFu) << 5) | ((d & 15u) << 1);
            }
        }

        // ---- 4 partition passes: fill -> drain -> barrier -> gather ----
        // (exposed waits are covered by the co-resident block's compute)
        BAR();   // prev chunk's gather<3>/epilogue done; c==0: lw/pad visible
        dma_fill(pnt, lds_all, 0, wv, lane);
        WAITVM0(); BAR();
        gather_phase<0>(lds_all, axs, axd, enc);

        BAR();
        dma_fill(pnt, lds_all, 1, wv, lane);
        WAITVM0(); BAR();
        gather_phase<1>(lds_all, axs, axd, enc);

        BAR();
        dma_fill(pnt, lds_all, 2, wv, lane);
        WAITVM0(); BAR();
        gather_phase<2>(lds_all, axs, axd, enc);

        BAR();
        dma_fill(pnt, lds_all, 3, wv, lane);
        WAITVM0(); BAR();
        gather_phase<3>(lds_all, axs, axd, enc);

        // ---- epilogue: per-graph segmented sum, 1 atomic/wave fast path ----
        int wb0 = __shfl(ebv[0][0], 0);      // first edge of wave window
        int wbL = __shfl(ebv[1][3], 63);     // last edge of wave window
        if (wb0 == wbL) {                    // sorted => whole window one graph
            float ssum = 0.0f;
            #pragma unroll
            for (int k = 0; k < EPT; ++k) ssum += lw[enc[k]];
            #pragma unroll
            for (int off = 32; off >= 1; off >>= 1)
                ssum += __shfl_down(ssum, off);
            if (lane == 0) atomicAdd(&out[wb0], ssum);
        } else {
            float acc = 0.0f; int cur = -1;
            #pragma unroll
            for (int k = 0; k < EPT; ++k) {
                int bb = ebv[k / 4][k % 4];  // static index
                if (bb != cur) {
                    if (cur >= 0) atomicAdd(&out[cur], acc);
                    cur = bb; acc = 0.0f;
                }
                acc += lw[enc[k]];
            }
            if (cur >= 0) atomicAdd(&out[cur], acc);
        }
    }
}

// Per-edge fallback / tail kernel (direct gathers; correctness path).
__global__ void edge_score_simple(const int* __restrict__ nt,
                                  const int* __restrict__ et,
                                  const int* __restrict__ es,
                                  const int* __restrict__ ed,
                                  const int* __restrict__ eb,
                                  const float* __restrict__ w,
                                  float* __restrict__ out,
                                  long e0, long E) {
    long e = e0 + (long)blockIdx.x * blockDim.x + threadIdx.x;
    if (e >= E) return;
    int enc = et[e] * 9 + nt[es[e]] * 3 + nt[ed[e]];
    atomicAdd(&out[eb[e]], w[enc]);
}

extern "C" void kernel_launch(void* const* d_in, const int* in_sizes, int n_in,
                              void* d_out, int out_size, void* d_ws, size_t ws_size,
                              hipStream_t stream) {
    const int*   node_type  = (const int*)d_in[0];
    const int*   edge_type  = (const int*)d_in[1];
    const int*   edge_index = (const int*)d_in[2];   // [2, E]: src then dst
    const int*   edge_batch = (const int*)d_in[3];
    const float* w          = (const float*)d_in[4];
    float* out = (float*)d_out;

    long N = in_sizes[0];
    long E = in_sizes[1];
    const int* esrc = edge_index;
    const int* edst = edge_index + E;

    // d_out is poisoned once and never re-poisoned between replays; we
    // accumulate with atomics, so zero it at the start of every launch.
    zero_kernel<<<(out_size + 255) / 256, 256, 0, stream>>>(out, out_size);

    int  nwords = (int)((N + 15) / 16);
    long nchunk = E / ((long)NBLK2 * CHUNK);           // 8 for E = 2^24
    bool fast_ok = (ws_size >= (size_t)nwords * 4) &&
                   (N <= (long)NPART * PART_NODES) && (nchunk > 0);

    if (fast_ok) {
        unsigned int* pnt = (unsigned int*)d_ws;
        pack_nt_kernel<<<(nwords + 255) / 256, 256, 0, stream>>>(node_type, pnt, nwords, (int)N);

        edge_score_k<<<NBLK2, THREADS, 0, stream>>>(
            pnt, edge_type, esrc, edst, edge_batch, w, out, (int)nchunk);

        long covered = (long)NBLK2 * nchunk * CHUNK;
        long rem     = E - covered;                    // 0 for this dataset
        if (rem > 0) {
            int tb = (int)((rem + 255) / 256);
            edge_score_simple<<<tb, 256, 0, stream>>>(
                node_type, edge_type, esrc, edst, edge_batch, w, out, covered, E);
        }
    } else {
        int tb = (int)((E + 255) / 256);
        edge_score_simple<<<tb, 256, 0, stream>>>(
            node_type, edge_type, esrc, edst, edge_batch, w, out, 0, E);
    }
}